// Round 10
// baseline (4936.769 us; speedup 1.0000x reference)
//
#include <hip/hip_runtime.h>

#define NH   12
#define ND   64
#define NHD  768   // NH*ND
#define NSEQ 4096
#define NIT  16
#define MM   256   // rows per iteration chunk

// LDS pitches (bf16 elements) — R2/R6-verified conflict behavior
#define T_P  264   // XT/ET pitch
#define W_P  72    // WBT pitch

typedef __bf16 bf16_t;
typedef bf16_t bf16x8 __attribute__((ext_vector_type(8)));
typedef float  f32x4  __attribute__((ext_vector_type(4)));

// native cast -> v_cvt_pk_bf16_f32 path (R9-validated: halves VALU busy)
static __device__ __forceinline__ unsigned short f2bf(float f) {
    union { __bf16 h; unsigned short u; } v; v.h = (__bf16)f; return v.u;
}

static __device__ __forceinline__ bf16x8 pack8(float4 a, float4 b) {
    union { unsigned short u[8]; bf16x8 v; } r;
    r.u[0] = f2bf(a.x); r.u[1] = f2bf(a.y); r.u[2] = f2bf(a.z); r.u[3] = f2bf(a.w);
    r.u[4] = f2bf(b.x); r.u[5] = f2bf(b.y); r.u[6] = f2bf(b.z); r.u[7] = f2bf(b.w);
    return r.v;
}

// Barrier draining ONLY LDS ops; global loads/stores stay in flight across it.
static __device__ __forceinline__ void barrier_lds() {
    asm volatile("s_waitcnt lgkmcnt(0)" ::: "memory");
    __builtin_amdgcn_s_barrier();
    asm volatile("" ::: "memory");
}

extern "C" __global__ void __launch_bounds__(1024)
ttt_fused(const float* __restrict__ qg, const float* __restrict__ kg,
          const float* __restrict__ vg, const float* __restrict__ Wi,
          float* __restrict__ outg)
{
    // two chains per block: team 0 = waves 0-7, team 1 = waves 8-15
    // 2*(33792+33792+9216) = 153600 B <= 160 KiB; 1 block/CU -> 128-VGPR budget
    __shared__ unsigned short XTs[2][64 * T_P] __attribute__((aligned(16)));
    __shared__ unsigned short ETs[2][64 * T_P] __attribute__((aligned(16)));
    __shared__ unsigned short WBs[2][64 * W_P] __attribute__((aligned(16)));

    const int tid  = threadIdx.x;
    const int team = tid >> 9;        // 0,1
    const int t    = tid & 511;       // thread-in-team
    const int wv   = t >> 6;          // wave-in-team 0..7
    const int lane = t & 63;
    const int g    = lane >> 4;       // 0..3
    const int ln   = lane & 15;       // 0..15

    const int bh = blockIdx.x * 2 + team;
    const int b  = bh / NH;
    const int h  = bh - b * NH;

    const float* kb = kg + (size_t)bh * NSEQ * ND;
    const float* vb = vg + (size_t)bh * NSEQ * ND;
    const float* qb = qg + (size_t)bh * NSEQ * ND;
    float* ob = outg + (size_t)b * NSEQ * NHD + h * ND;

    unsigned short* xt  = XTs[team];   // x_tr transposed [d][m]
    unsigned short* etb = ETs[team];   // err [e][m]
    unsigned short* wbt = WBs[team];   // W transposed bf16 [e][d]

    const int r0  = wv << 5;           // wave's 32-row m-slice (A and C), tiles r0, r0+16
    const int d0  = (wv & 3) << 4;     // grad tile d
    const int e0b = (wv >> 2) << 5;    // grad tiles e = e0b, e0b+16
    const float scale = 1.0f / 16384.0f;   // LR / (m*D)

    // staging ownership: thread -> rows (rp, rp+1) x cols dh..dh+15
    const int rp = (t & 127) << 1;
    const int dh = ((t >> 7) & 3) << 4;

    // ---- prologue: chunk-0 loads
    float4 ks[8];   // 2 rows x 16 cols f32
    {
        const float* kr = kb + (size_t)rp * ND + dh;
        #pragma unroll
        for (int i = 0; i < 4; ++i) {
            ks[i]     = *(const float4*)(kr + 4 * i);
            ks[4 + i] = *(const float4*)(kr + ND + 4 * i);
        }
    }
    float vq[32];   // vq[ms*16+et*4+j] = y[r0+ms*16+g*4+j][et*16+ln]
    {
        const float* vp = vb + (size_t)r0 * ND;
        #pragma unroll
        for (int ms = 0; ms < 2; ++ms)
            #pragma unroll
            for (int et = 0; et < 4; ++et)
                #pragma unroll
                for (int j = 0; j < 4; ++j)
                    vq[ms * 16 + et * 4 + j] = vp[(size_t)(ms * 16 + g * 4 + j) * ND + et * 16 + ln];
    }
    float wf[8];    // wf[t2*4+j] = W[d0+g*4+j][e0b+t2*16+ln]
    {
        const float* wp = Wi + (size_t)h * ND * ND;
        #pragma unroll
        for (int t2 = 0; t2 < 2; ++t2) {
            ushort4 wq; unsigned short* wqp = (unsigned short*)&wq;
            #pragma unroll
            for (int j = 0; j < 4; ++j) {
                wf[t2 * 4 + j] = wp[(size_t)(d0 + g * 4 + j) * ND + e0b + t2 * 16 + ln];
                wqp[j] = f2bf(wf[t2 * 4 + j]);
            }
            *(ushort4*)&wbt[(e0b + t2 * 16 + ln) * W_P + d0 + g * 4] = wq;
        }
    }
    // stage XT(0)
    #pragma unroll
    for (int j = 0; j < 16; ++j) {
        float lo = ((const float*)&ks[j >> 2])[j & 3];
        float hi = ((const float*)&ks[4 + (j >> 2)])[j & 3];
        *(unsigned*)&xt[(dh + j) * T_P + rp] = (unsigned)f2bf(lo) | ((unsigned)f2bf(hi) << 16);
    }
    float4 qr[8];
    barrier_lds();   // XT(0), WBT(W_0) visible

    for (int it = 0; it < NIT; ++it) {
        // ================= region 1: stage XT(it) | A(it) | C(it-1) =================
        if (it > 0) {
            #pragma unroll
            for (int j = 0; j < 16; ++j) {
                float lo = ((const float*)&ks[j >> 2])[j & 3];
                float hi = ((const float*)&ks[4 + (j >> 2)])[j & 3];
                *(unsigned*)&xt[(dh + j) * T_P + rp] = (unsigned)f2bf(lo) | ((unsigned)f2bf(hi) << 16);
            }
        }

        #pragma unroll
        for (int ms = 0; ms < 2; ++ms) {
            // JIT x fragment (k chunk staged last region -> L2-hot)
            const float* xp = kb + ((size_t)(it * MM) + r0 + ms * 16 + ln) * ND;
            float4 x0 = *(const float4*)(xp + g * 8);
            float4 x1 = *(const float4*)(xp + g * 8 + 4);
            float4 x2 = *(const float4*)(xp + 32 + g * 8);
            float4 x3 = *(const float4*)(xp + 32 + g * 8 + 4);
            bf16x8 xa0 = pack8(x0, x1);
            bf16x8 xa1 = pack8(x2, x3);
            bf16x8 aq0, aq1;
            if (it > 0) {
                aq0 = pack8(qr[ms * 4 + 0], qr[ms * 4 + 1]);
                aq1 = pack8(qr[ms * 4 + 2], qr[ms * 4 + 3]);
            }
            #pragma unroll
            for (int et = 0; et < 4; ++et) {
                // one WBT fragment serves A and C (B-operand both times)
                bf16x8 w0 = *(const bf16x8*)&wbt[(et * 16 + ln) * W_P + g * 8];
                bf16x8 w1 = *(const bf16x8*)&wbt[(et * 16 + ln) * W_P + 32 + g * 8];

                // A(it): err[m][e] = x W - y -> ET (vector ushort4 write, R7-verified)
                f32x4 ae = {0.f, 0.f, 0.f, 0.f};
                ae = __builtin_amdgcn_mfma_f32_16x16x32_bf16(xa0, w0, ae, 0, 0, 0);
                ae = __builtin_amdgcn_mfma_f32_16x16x32_bf16(xa1, w1, ae, 0, 0, 0);
                ushort4 ew; unsigned short* ewp = (unsigned short*)&ew;
                ewp[0] = f2bf(ae[0] - vq[ms * 16 + et * 4 + 0]);
                ewp[1] = f2bf(ae[1] - vq[ms * 16 + et * 4 + 1]);
                ewp[2] = f2bf(ae[2] - vq[ms * 16 + et * 4 + 2]);
                ewp[3] = f2bf(ae[3] - vq[ms * 16 + et * 4 + 3]);
                *(ushort4*)&etb[(et * 16 + ln) * T_P + r0 + ms * 16 + g * 4] = ew;

                // C(it-1): out = x_te * W_it
                if (it > 0) {
                    f32x4 oc = {0.f, 0.f, 0.f, 0.f};
                    oc = __builtin_amdgcn_mfma_f32_16x16x32_bf16(aq0, w0, oc, 0, 0, 0);
                    oc = __builtin_amdgcn_mfma_f32_16x16x32_bf16(aq1, w1, oc, 0, 0, 0);
                    #pragma unroll
                    for (int j = 0; j < 4; ++j)
                        ob[((size_t)((it - 1) * MM) + r0 + ms * 16 + g * 4 + j) * NHD + et * 16 + ln] = oc[j];
                }
            }
        }

        barrier_lds();   // alpha: XT(it), ET(it) visible

        // ================= region 2: issue ks(it+1) | B(it) | issue vq/qr =================
        if (it + 1 < NIT) {
            const float* kr = kb + ((size_t)((it + 1) * MM) + rp) * ND + dh;
            #pragma unroll
            for (int i = 0; i < 4; ++i) {
                ks[i]     = *(const float4*)(kr + 4 * i);
                ks[4 + i] = *(const float4*)(kr + ND + 4 * i);
            }
        }

        // B(it): grad = x_tr^T err ; wf -= scale*grad ; WBT <- W_{it+1}
        #pragma unroll
        for (int t2 = 0; t2 < 2; ++t2) {
            const int e0 = e0b + t2 * 16;
            f32x4 ga = {0.f, 0.f, 0.f, 0.f};
            #pragma unroll
            for (int kx = 0; kx < 8; ++kx) {
                bf16x8 af  = *(const bf16x8*)&xt[(d0 + ln) * T_P + kx * 32 + g * 8];
                bf16x8 bf_ = *(const bf16x8*)&etb[(e0 + ln) * T_P + kx * 32 + g * 8];
                ga = __builtin_amdgcn_mfma_f32_16x16x32_bf16(af, bf_, ga, 0, 0, 0);
            }
            ushort4 wq; unsigned short* wqp = (unsigned short*)&wq;
            #pragma unroll
            for (int j = 0; j < 4; ++j) {
                wf[t2 * 4 + j] -= scale * ga[j];
                wqp[j] = f2bf(wf[t2 * 4 + j]);
            }
            *(ushort4*)&wbt[(e0 + ln) * W_P + d0 + g * 4] = wq;
        }

        // prefetch issues (consumed next region 1; in flight across beta only)
        if (it + 1 < NIT) {
            const float* vp = vb + ((size_t)((it + 1) * MM) + r0) * ND;
            #pragma unroll
            for (int ms = 0; ms < 2; ++ms)
                #pragma unroll
                for (int et = 0; et < 4; ++et)
                    #pragma unroll
                    for (int j = 0; j < 4; ++j)
                        vq[ms * 16 + et * 4 + j] = vp[(size_t)(ms * 16 + g * 4 + j) * ND + et * 16 + ln];
        }
        #pragma unroll
        for (int ms = 0; ms < 2; ++ms) {
            const float* qp = qb + ((size_t)(it * MM) + r0 + ms * 16 + ln) * ND;
            qr[ms * 4 + 0] = *(const float4*)(qp + g * 8);
            qr[ms * 4 + 1] = *(const float4*)(qp + g * 8 + 4);
            qr[ms * 4 + 2] = *(const float4*)(qp + 32 + g * 8);
            qr[ms * 4 + 3] = *(const float4*)(qp + 32 + g * 8 + 4);
        }

        barrier_lds();   // beta: WBT(W_{it+1}) visible; XT free for overwrite
    }

    // ================= epilogue: C(NIT-1) with W_NIT =================
    #pragma unroll
    for (int ms = 0; ms < 2; ++ms) {
        bf16x8 aq0 = pack8(qr[ms * 4 + 0], qr[ms * 4 + 1]);
        bf16x8 aq1 = pack8(qr[ms * 4 + 2], qr[ms * 4 + 3]);
        #pragma unroll
        for (int et = 0; et < 4; ++et) {
            bf16x8 w0 = *(const bf16x8*)&wbt[(et * 16 + ln) * W_P + g * 8];
            bf16x8 w1 = *(const bf16x8*)&wbt[(et * 16 + ln) * W_P + 32 + g * 8];
            f32x4 oc = {0.f, 0.f, 0.f, 0.f};
            oc = __builtin_amdgcn_mfma_f32_16x16x32_bf16(aq0, w0, oc, 0, 0, 0);
            oc = __builtin_amdgcn_mfma_f32_16x16x32_bf16(aq1, w1, oc, 0, 0, 0);
            #pragma unroll
            for (int j = 0; j < 4; ++j)
                ob[((size_t)((NIT - 1) * MM) + r0 + ms * 16 + g * 4 + j) * NHD + et * 16 + ln] = oc[j];
        }
    }
}

extern "C" void kernel_launch(void* const* d_in, const int* in_sizes, int n_in,
                              void* d_out, int out_size, void* d_ws, size_t ws_size,
                              hipStream_t stream) {
    const float* q  = (const float*)d_in[0];
    const float* k  = (const float*)d_in[1];
    const float* v  = (const float*)d_in[2];
    const float* Wi = (const float*)d_in[3];
    float* out = (float*)d_out;

    int nbh  = in_sizes[0] / (NSEQ * ND);   // 192
    int grid = nbh / 2;                     // 96 blocks x 2 chains
    hipLaunchKernelGGL(ttt_fused, dim3(grid), dim3(1024), 0, stream,
                       q, k, v, Wi, out);
}

// Round 11
// 196.575 us; speedup vs baseline: 25.1139x; 25.1139x over previous
//
#include <hip/hip_runtime.h>

#define NH   12
#define ND   64
#define NHD  768   // NH*ND
#define NSEQ 4096
#define NIT  16
#define MM   256   // rows per iteration chunk

// LDS pitches (bf16 elements) — R2/R6/R10-verified conflict behavior (<=2-way)
#define T_P  264   // XT/ET pitch
#define W_P  72    // WBT pitch

typedef __bf16 bf16_t;
typedef bf16_t bf16x8 __attribute__((ext_vector_type(8)));
typedef float  f32x4  __attribute__((ext_vector_type(4)));

// native cast -> v_cvt_pk_bf16_f32 path (R9-validated: halves VALU busy)
static __device__ __forceinline__ unsigned short f2bf(float f) {
    union { __bf16 h; unsigned short u; } v; v.h = (__bf16)f; return v.u;
}

static __device__ __forceinline__ bf16x8 pack8(float4 a, float4 b) {
    union { unsigned short u[8]; bf16x8 v; } r;
    r.u[0] = f2bf(a.x); r.u[1] = f2bf(a.y); r.u[2] = f2bf(a.z); r.u[3] = f2bf(a.w);
    r.u[4] = f2bf(b.x); r.u[5] = f2bf(b.y); r.u[6] = f2bf(b.z); r.u[7] = f2bf(b.w);
    return r.v;
}

// Barrier draining ONLY LDS ops; global loads/stores stay in flight across it.
static __device__ __forceinline__ void barrier_lds() {
    asm volatile("s_waitcnt lgkmcnt(0)" ::: "memory");
    __builtin_amdgcn_s_barrier();
    asm volatile("" ::: "memory");
}

extern "C" __global__ void __launch_bounds__(512)
ttt_fused(const float* __restrict__ qg, const float* __restrict__ kg,
          const float* __restrict__ vg, const float* __restrict__ Wi,
          float* __restrict__ outg)
{
    // one chain per 512-thread block (8 waves); 76800 B LDS
    // 512-thread blocks: allocator grants ~116-128 VGPRs (R8 evidence) -> prefetch
    // set (ks+vq+qr+wf ~104 regs) stays in registers across barriers.
    __shared__ unsigned short XT[64 * T_P] __attribute__((aligned(16)));
    __shared__ unsigned short ET[64 * T_P] __attribute__((aligned(16)));
    __shared__ unsigned short WBT[64 * W_P] __attribute__((aligned(16)));

    const int tid  = threadIdx.x;
    const int wv   = tid >> 6;        // wave 0..7
    const int lane = tid & 63;
    const int g    = lane >> 4;       // 0..3
    const int ln   = lane & 15;       // 0..15

    const int bh = blockIdx.x;
    const int b  = bh / NH;
    const int h  = bh - b * NH;

    const float* kb = kg + (size_t)bh * NSEQ * ND;
    const float* vb = vg + (size_t)bh * NSEQ * ND;
    const float* qb = qg + (size_t)bh * NSEQ * ND;
    float* ob = outg + (size_t)b * NSEQ * NHD + h * ND;

    const int r0  = wv << 5;           // wave's 32-row m-slice (A and C)
    const int d0  = (wv & 3) << 4;     // grad tile d
    const int e0b = (wv >> 2) << 5;    // grad tiles e = e0b, e0b+16
    const float scale = 1.0f / 16384.0f;   // LR / (m*D)

    // staging ownership: thread -> rows (rp, rp+1) x cols dh..dh+15
    const int rp = (tid & 127) << 1;
    const int dh = ((tid >> 7) & 3) << 4;

    // ---- prologue: chunk-0 loads
    float4 ks[8];   // 2 rows x 16 cols f32
    {
        const float* kr = kb + (size_t)rp * ND + dh;
        #pragma unroll
        for (int i = 0; i < 4; ++i) {
            ks[i]     = *(const float4*)(kr + 4 * i);
            ks[4 + i] = *(const float4*)(kr + ND + 4 * i);
        }
    }
    float vq[32];   // vq[ms*16+et*4+j] = y[r0+ms*16+g*4+j][et*16+ln]
    {
        const float* vp = vb + (size_t)r0 * ND;
        #pragma unroll
        for (int ms = 0; ms < 2; ++ms)
            #pragma unroll
            for (int et = 0; et < 4; ++et)
                #pragma unroll
                for (int j = 0; j < 4; ++j)
                    vq[ms * 16 + et * 4 + j] = vp[(size_t)(ms * 16 + g * 4 + j) * ND + et * 16 + ln];
    }
    float wf[8];    // wf[t2*4+j] = W[d0+g*4+j][e0b+t2*16+ln]
    {
        const float* wp = Wi + (size_t)h * ND * ND;
        #pragma unroll
        for (int t2 = 0; t2 < 2; ++t2) {
            ushort4 wq; unsigned short* wqp = (unsigned short*)&wq;
            #pragma unroll
            for (int j = 0; j < 4; ++j) {
                wf[t2 * 4 + j] = wp[(size_t)(d0 + g * 4 + j) * ND + e0b + t2 * 16 + ln];
                wqp[j] = f2bf(wf[t2 * 4 + j]);
            }
            *(ushort4*)&WBT[(e0b + t2 * 16 + ln) * W_P + d0 + g * 4] = wq;
        }
    }
    // stage XT(0)
    #pragma unroll
    for (int j = 0; j < 16; ++j) {
        float lo = ((const float*)&ks[j >> 2])[j & 3];
        float hi = ((const float*)&ks[4 + (j >> 2)])[j & 3];
        *(unsigned*)&XT[(dh + j) * T_P + rp] = (unsigned)f2bf(lo) | ((unsigned)f2bf(hi) << 16);
    }
    float4 qr[8];
    barrier_lds();   // XT(0), WBT(W_0) visible

    for (int it = 0; it < NIT; ++it) {
        // ================= region 1: stage XT(it) | A(it) | C(it-1) =================
        if (it > 0) {
            #pragma unroll
            for (int j = 0; j < 16; ++j) {
                float lo = ((const float*)&ks[j >> 2])[j & 3];
                float hi = ((const float*)&ks[4 + (j >> 2)])[j & 3];
                *(unsigned*)&XT[(dh + j) * T_P + rp] = (unsigned)f2bf(lo) | ((unsigned)f2bf(hi) << 16);
            }
        }

        #pragma unroll
        for (int ms = 0; ms < 2; ++ms) {
            // JIT x fragment (k chunk staged last region -> L2-hot)
            const float* xp = kb + ((size_t)(it * MM) + r0 + ms * 16 + ln) * ND;
            float4 x0 = *(const float4*)(xp + g * 8);
            float4 x1 = *(const float4*)(xp + g * 8 + 4);
            float4 x2 = *(const float4*)(xp + 32 + g * 8);
            float4 x3 = *(const float4*)(xp + 32 + g * 8 + 4);
            bf16x8 xa0 = pack8(x0, x1);
            bf16x8 xa1 = pack8(x2, x3);
            bf16x8 aq0, aq1;
            if (it > 0) {
                aq0 = pack8(qr[ms * 4 + 0], qr[ms * 4 + 1]);
                aq1 = pack8(qr[ms * 4 + 2], qr[ms * 4 + 3]);
            }
            #pragma unroll
            for (int et = 0; et < 4; ++et) {
                // one WBT fragment serves A and C (B-operand both times)
                bf16x8 w0 = *(const bf16x8*)&WBT[(et * 16 + ln) * W_P + g * 8];
                bf16x8 w1 = *(const bf16x8*)&WBT[(et * 16 + ln) * W_P + 32 + g * 8];

                // A(it): err[m][e] = x W - y -> ET (vector ushort4 write)
                f32x4 ae = {0.f, 0.f, 0.f, 0.f};
                ae = __builtin_amdgcn_mfma_f32_16x16x32_bf16(xa0, w0, ae, 0, 0, 0);
                ae = __builtin_amdgcn_mfma_f32_16x16x32_bf16(xa1, w1, ae, 0, 0, 0);
                ushort4 ew; unsigned short* ewp = (unsigned short*)&ew;
                ewp[0] = f2bf(ae[0] - vq[ms * 16 + et * 4 + 0]);
                ewp[1] = f2bf(ae[1] - vq[ms * 16 + et * 4 + 1]);
                ewp[2] = f2bf(ae[2] - vq[ms * 16 + et * 4 + 2]);
                ewp[3] = f2bf(ae[3] - vq[ms * 16 + et * 4 + 3]);
                *(ushort4*)&ET[(et * 16 + ln) * T_P + r0 + ms * 16 + g * 4] = ew;

                // C(it-1): out = x_te * W_it
                if (it > 0) {
                    f32x4 oc = {0.f, 0.f, 0.f, 0.f};
                    oc = __builtin_amdgcn_mfma_f32_16x16x32_bf16(aq0, w0, oc, 0, 0, 0);
                    oc = __builtin_amdgcn_mfma_f32_16x16x32_bf16(aq1, w1, oc, 0, 0, 0);
                    #pragma unroll
                    for (int j = 0; j < 4; ++j)
                        ob[((size_t)((it - 1) * MM) + r0 + ms * 16 + g * 4 + j) * NHD + et * 16 + ln] = oc[j];
                }
            }
        }

        barrier_lds();   // alpha: XT(it), ET(it) visible

        // ================= region 2: issue ks(it+1) | B(it) | issue vq/qr =================
        if (it + 1 < NIT) {
            const float* kr = kb + ((size_t)((it + 1) * MM) + rp) * ND + dh;
            #pragma unroll
            for (int i = 0; i < 4; ++i) {
                ks[i]     = *(const float4*)(kr + 4 * i);
                ks[4 + i] = *(const float4*)(kr + ND + 4 * i);
            }
        }

        // B(it): grad = x_tr^T err ; wf -= scale*grad ; WBT <- W_{it+1}
        #pragma unroll
        for (int t2 = 0; t2 < 2; ++t2) {
            const int e0 = e0b + t2 * 16;
            f32x4 ga = {0.f, 0.f, 0.f, 0.f};
            #pragma unroll
            for (int kx = 0; kx < 8; ++kx) {
                bf16x8 af  = *(const bf16x8*)&XT[(d0 + ln) * T_P + kx * 32 + g * 8];
                bf16x8 bf_ = *(const bf16x8*)&ET[(e0 + ln) * T_P + kx * 32 + g * 8];
                ga = __builtin_amdgcn_mfma_f32_16x16x32_bf16(af, bf_, ga, 0, 0, 0);
            }
            ushort4 wq; unsigned short* wqp = (unsigned short*)&wq;
            #pragma unroll
            for (int j = 0; j < 4; ++j) {
                wf[t2 * 4 + j] -= scale * ga[j];
                wqp[j] = f2bf(wf[t2 * 4 + j]);
            }
            *(ushort4*)&WBT[(e0 + ln) * W_P + d0 + g * 4] = wq;
        }

        // prefetch issues (consumed next region 1; in flight across beta only)
        if (it + 1 < NIT) {
            const float* vp = vb + ((size_t)((it + 1) * MM) + r0) * ND;
            #pragma unroll
            for (int ms = 0; ms < 2; ++ms)
                #pragma unroll
                for (int et = 0; et < 4; ++et)
                    #pragma unroll
                    for (int j = 0; j < 4; ++j)
                        vq[ms * 16 + et * 4 + j] = vp[(size_t)(ms * 16 + g * 4 + j) * ND + et * 16 + ln];
        }
        #pragma unroll
        for (int ms = 0; ms < 2; ++ms) {
            const float* qp = qb + ((size_t)(it * MM) + r0 + ms * 16 + ln) * ND;
            qr[ms * 4 + 0] = *(const float4*)(qp + g * 8);
            qr[ms * 4 + 1] = *(const float4*)(qp + g * 8 + 4);
            qr[ms * 4 + 2] = *(const float4*)(qp + 32 + g * 8);
            qr[ms * 4 + 3] = *(const float4*)(qp + 32 + g * 8 + 4);
        }

        barrier_lds();   // beta: WBT(W_{it+1}) visible; XT free for overwrite
    }

    // ================= epilogue: C(NIT-1) with W_NIT =================
    #pragma unroll
    for (int ms = 0; ms < 2; ++ms) {
        bf16x8 aq0 = pack8(qr[ms * 4 + 0], qr[ms * 4 + 1]);
        bf16x8 aq1 = pack8(qr[ms * 4 + 2], qr[ms * 4 + 3]);
        #pragma unroll
        for (int et = 0; et < 4; ++et) {
            bf16x8 w0 = *(const bf16x8*)&WBT[(et * 16 + ln) * W_P + g * 8];
            bf16x8 w1 = *(const bf16x8*)&WBT[(et * 16 + ln) * W_P + 32 + g * 8];
            f32x4 oc = {0.f, 0.f, 0.f, 0.f};
            oc = __builtin_amdgcn_mfma_f32_16x16x32_bf16(aq0, w0, oc, 0, 0, 0);
            oc = __builtin_amdgcn_mfma_f32_16x16x32_bf16(aq1, w1, oc, 0, 0, 0);
            #pragma unroll
            for (int j = 0; j < 4; ++j)
                ob[((size_t)((NIT - 1) * MM) + r0 + ms * 16 + g * 4 + j) * NHD + et * 16 + ln] = oc[j];
        }
    }
}

extern "C" void kernel_launch(void* const* d_in, const int* in_sizes, int n_in,
                              void* d_out, int out_size, void* d_ws, size_t ws_size,
                              hipStream_t stream) {
    const float* q  = (const float*)d_in[0];
    const float* k  = (const float*)d_in[1];
    const float* v  = (const float*)d_in[2];
    const float* Wi = (const float*)d_in[3];
    float* out = (float*)d_out;

    int nbh = in_sizes[0] / (NSEQ * ND);   // 192
    hipLaunchKernelGGL(ttt_fused, dim3(nbh), dim3(512), 0, stream,
                       q, k, v, Wi, out);
}